// Round 3
// baseline (2681.244 us; speedup 1.0000x reference)
//
#include <hip/hip_runtime.h>
#include <stdint.h>

typedef __attribute__((ext_vector_type(8))) short short8;
typedef __attribute__((ext_vector_type(4))) float f32x4;

// Problem constants (fixed by the reference): B=2048 traj, T=32, I=H=1024
#define NTRAJ 2048
#define TSTEP 32
#define HDIM  1024
#define KCAT  2048   // I + H
#define NGATE 4096   // 4*H

__device__ __forceinline__ unsigned short f2bf(float f) {
  union { float f; unsigned int u; } v; v.f = f;
  unsigned int u = v.u + 0x7FFFu + ((v.u >> 16) & 1u);   // RNE
  return (unsigned short)(u >> 16);
}
__device__ __forceinline__ float sigmoidf_(float x) {
  return 1.0f / (1.0f + __expf(-x));
}
__device__ __forceinline__ float tanhf_(float x) {
  return 1.0f - 2.0f / (__expf(2.0f * x) + 1.0f);
}

// async global -> LDS, 16B per lane. LDS dest is wave-uniform base + lane*16.
__device__ __forceinline__ void async_lds16(const void* g, void* l) {
  __builtin_amdgcn_global_load_lds(
      (const __attribute__((address_space(1))) unsigned int*)g,
      (__attribute__((address_space(3))) unsigned int*)l, 16, 0, 0);
}

// ---------------- prep kernels ----------------

// fp32 -> bf16 AND transpose to time-major X[t][traj][1024]
__global__ void cvt_bf16_kernel(const float* __restrict__ src,
                                unsigned short* __restrict__ dst, int n4) {
  int i = blockIdx.x * blockDim.x + threadIdx.x;
  if (i >= n4) return;
  float4 v = ((const float4*)src)[i];
  int e = i * 4;
  int row = e >> 10;            // traj*32 + t
  int col = e & 1023;
  int traj = row >> 5, tt = row & 31;
  size_t de = (((size_t)tt * 2048 + traj) << 10) + col;
  ushort4 o;
  o.x = f2bf(v.x); o.y = f2bf(v.y); o.z = f2bf(v.z); o.w = f2bf(v.w);
  *(ushort4*)&dst[de] = o;
}

// Build Wcat[4096][2048] bf16 = [w_ih | w_hh] (both stored row-major [4096][1024])
__global__ void wcat_kernel(const float* __restrict__ wih,
                            const float* __restrict__ whh,
                            unsigned short* __restrict__ wcat) {
  int i = blockIdx.x * blockDim.x + threadIdx.x;   // float4 index, 2,097,152 total
  int e = i * 4;
  int row = e >> 11;           // /2048
  int col = e & 2047;
  const float* src = (col < 1024) ? (wih + (size_t)row * 1024 + col)
                                  : (whh + (size_t)row * 1024 + (col - 1024));
  float4 v = *(const float4*)src;
  ushort4 o;
  o.x = f2bf(v.x); o.y = f2bf(v.y); o.z = f2bf(v.z); o.w = f2bf(v.w);
  ((ushort4*)wcat)[i] = o;
}

// h0 (bf16), c0 (fp32), bias = b_ih + b_hh
__global__ void state_prep(const float* __restrict__ rnn,
                           const float* __restrict__ bih,
                           const float* __restrict__ bhh,
                           unsigned short* __restrict__ h0,
                           float* __restrict__ c0,
                           float* __restrict__ bias) {
  int i = blockIdx.x * blockDim.x + threadIdx.x;   // 0..2097151
  int b = i >> 10, j = i & 1023;
  float hv = rnn[(size_t)b * 2048 + j];
  float cv = rnn[(size_t)b * 2048 + 1024 + j];
  h0[i] = f2bf(hv);
  c0[i] = cv;
  if (i < 4096) bias[i] = bih[i] + bhh[i];
}

// ---------------- fused recurrent step ----------------
// gates = [x_t | h] @ Wcat^T + bias ; LSTM cell update fused, register-local.
// Block: 256 thr (4 waves). Wave w owns 64 batch rows x 16 h-cols x ALL 4 gates.
// XCD-aware mapping: XCD k owns column-groups y in {2k,2k+1} -> 2MB B set in L2.
// Pipeline: 2-deep LDS double-buffer, ONE __syncthreads per K-step; the
// vmcnt(0) drain at the barrier waits for loads issued BEFORE this K-step's
// ds_read+MFMA, so load latency is hidden under compute (T3-minimum recipe).
// Bank conflicts: 64B-row tiles read as b128 were 8-way; both-sides XOR
// swizzle (slot ^= (row>>1)&3; linear LDS dest + pre-swizzled per-lane global
// source + swizzled read, rule #21) -> residual 2-way (free).
__global__ __launch_bounds__(256, 2)
void lstm_step(const unsigned short* __restrict__ X,     // [32][2048][1024] bf16
               const unsigned short* __restrict__ Wcat,  // [4096][2048] bf16
               const float* __restrict__ bias,           // [4096]
               const float* __restrict__ dones,          // [65536]
               const unsigned short* __restrict__ h_in,  // [2048][1024] bf16
               unsigned short* __restrict__ h_out,       // [2048][1024] bf16
               float* __restrict__ cbuf,                 // [2048][1024] fp32
               float* __restrict__ out,                  // x_out [65536][1024]
               float* __restrict__ rnn_out,              // [2048][2048]
               int t) {
  __shared__ __align__(16) unsigned short Ab[2][64 * 32];       // 2 x 4KB
  __shared__ __align__(16) unsigned short Bb[2][4 * 64 * 32];   // 2 x 16KB

  const int tid  = threadIdx.x;
  const int wave = tid >> 6;
  const int lane = tid & 63;
  const int l16  = lane & 15;
  const int quad = lane >> 4;

  // XCD-aware block decode (bijective over 512 blocks; HW round-robins s&7)
  const int sbid = blockIdx.x;       // 0..511
  const int xcd  = sbid & 7;
  const int ii   = sbid >> 3;        // 0..63
  const int by   = (xcd << 1) | (ii >> 5);   // 0..15  (col group)
  const int bx   = ii & 31;                  // 0..31  (batch group)
  const int bBase = bx * 64;   // batch rows
  const int n0    = by * 64;   // cols within one gate (0..1023)

  // this thread's output column (C layout col = lane&15)
  const int col = n0 + wave * 16 + l16;

  // swizzled read slot: logical slot `quad` of row l16 lives at sq
  const int sq = quad ^ ((l16 >> 1) & 3);

  // accumulators init with bias
  f32x4 acc[4][4];
#pragma unroll
  for (int g = 0; g < 4; ++g) {
    float bv = bias[g * 1024 + col];
    f32x4 b4 = {bv, bv, bv, bv};
#pragma unroll
    for (int mt = 0; mt < 4; ++mt) acc[mt][g] = b4;
  }

  // staging: 1KB chunk = 16 rows x 32 bf16. Linear LDS dest (lane*16B) means
  // LDS slot (lr, lane&3) receives the global slot we point at -> pre-swizzle
  // the per-lane global source slot so LDS holds the swizzled layout.
  const int lr = lane >> 2;
  const int lc = ((lane & 3) ^ ((lr >> 1) & 3)) * 8;   // pre-swizzled source col
  const unsigned short* aX =
      X + (((size_t)t * 2048) + bBase + wave * 16 + lr) * 1024 + lc;
  const unsigned short* aH =
      h_in + (size_t)(bBase + wave * 16 + lr) * 1024 + lc;

  const unsigned short* bS[4];
#pragma unroll
  for (int q = 0; q < 4; ++q) {
    int cb = wave + 4 * q;                       // B chunk id (g = q, rowblk = wave)
    int g  = cb >> 2;
    int row = g * 1024 + n0 + (cb & 3) * 16 + lr;
    bS[q] = Wcat + (size_t)row * 2048 + lc;
  }

  // stage K-step j into buffer b
  auto stage = [&](int j, int b) {
    const unsigned short* as =
        (j < 32) ? (aX + (size_t)j * 32) : (aH + (size_t)(j - 32) * 32);
    async_lds16(as, &Ab[b][wave * 512]);
#pragma unroll
    for (int q = 0; q < 4; ++q)
      async_lds16(bS[q] + (size_t)j * 32, &Bb[b][(wave + 4 * q) * 512]);
  };

  // compute K-step from buffer b
  auto compute = [&](int b) {
    short8 fa[4], fb[4];
#pragma unroll
    for (int mt = 0; mt < 4; ++mt)
      fa[mt] = *(const short8*)&Ab[b][mt * 512 + l16 * 32 + sq * 8];
#pragma unroll
    for (int g = 0; g < 4; ++g)
      fb[g] = *(const short8*)&Bb[b][(g * 4 + wave) * 512 + l16 * 32 + sq * 8];
#pragma unroll
    for (int mt = 0; mt < 4; ++mt)
#pragma unroll
      for (int g = 0; g < 4; ++g)
        acc[mt][g] = __builtin_amdgcn_mfma_f32_16x16x32_bf16(fa[mt], fb[g],
                                                             acc[mt][g], 0, 0, 0);
  };

  // prologue: fill buffer 0 (one exposed latency, amortized over 64 K-steps)
  stage(0, 0);
  __syncthreads();

  for (int j = 0; j < 64; ++j) {
    const int cur = j & 1;
    if (j < 63) stage(j + 1, cur ^ 1);   // prefetch next K-step
    compute(cur);                         // hides prefetch latency
    __syncthreads();                      // vmcnt(0)+barrier: prefetch landed,
                                          // all reads of buf[cur] done
  }

  // epilogue: fully register-local. lane holds rows mt*16+quad*4+v, col `col`.
#pragma unroll
  for (int mt = 0; mt < 4; ++mt) {
#pragma unroll
    for (int v = 0; v < 4; ++v) {
      int b = bBase + mt * 16 + quad * 4 + v;
      float gi = sigmoidf_(acc[mt][0][v]);
      float gf = sigmoidf_(acc[mt][1][v]);
      float gg = tanhf_  (acc[mt][2][v]);
      float go = sigmoidf_(acc[mt][3][v]);
      float cold = cbuf[(size_t)b * 1024 + col];
      float cn = gf * cold + gi * gg;
      float hn = go * tanhf_(cn);
      out[((size_t)b * 32 + t) * 1024 + col] = hn;       // x_out (pre-reset h)
      // fold NEXT step's reset into the carries; step t+1 reset = dones[b*32+t]
      float keep = (t < 31) ? (1.0f - dones[b * 32 + t]) : 1.0f;
      cbuf[(size_t)b * 1024 + col] = cn * keep;
      h_out[(size_t)b * 1024 + col] = f2bf(hn * keep);
      if (t == 31) {                                      // final states, un-reset
        rnn_out[(size_t)b * 2048 + col] = hn;
        rnn_out[(size_t)b * 2048 + 1024 + col] = cn;
      }
    }
  }
}

// ---------------- launcher ----------------
extern "C" void kernel_launch(void* const* d_in, const int* in_sizes, int n_in,
                              void* d_out, int out_size, void* d_ws, size_t ws_size,
                              hipStream_t stream) {
  (void)in_sizes; (void)n_in; (void)out_size; (void)ws_size;
  const float* head  = (const float*)d_in[0];  // [65536][1024]
  const float* rnn   = (const float*)d_in[1];  // [2048][2048]
  const float* dones = (const float*)d_in[2];  // [65536]
  const float* wih   = (const float*)d_in[3];  // [4096][1024]
  const float* whh   = (const float*)d_in[4];  // [4096][1024]
  const float* bih   = (const float*)d_in[5];  // [4096]
  const float* bhh   = (const float*)d_in[6];  // [4096]
  float* out = (float*)d_out;
  float* rnn_out = out + (size_t)65536 * 1024;

  char* ws = (char*)d_ws;
  unsigned short* X    = (unsigned short*)(ws);                 // 128 MB (time-major)
  unsigned short* Wcat = (unsigned short*)(ws + 134217728);     // 16 MB
  float*          bias = (float*)(ws + 150994944);              // 16 KB
  unsigned short* h0   = (unsigned short*)(ws + 151011328);     // 4 MB
  unsigned short* h1   = (unsigned short*)(ws + 155205632);     // 4 MB
  float*          cbuf = (float*)(ws + 159399936);              // 8 MB
  // total ws use: ~160 MB

  cvt_bf16_kernel<<<65536, 256, 0, stream>>>(head, X, 16777216);
  wcat_kernel<<<8192, 256, 0, stream>>>(wih, whh, Wcat);
  state_prep<<<8192, 256, 0, stream>>>(rnn, bih, bhh, h0, cbuf, bias);

  unsigned short* hb[2] = {h0, h1};
  for (int t = 0; t < TSTEP; ++t) {
    lstm_step<<<512, 256, 0, stream>>>(
        X, Wcat, bias, dones, hb[t & 1], hb[(t + 1) & 1], cbuf, out, rnn_out, t);
  }
}

// Round 5
// 2652.082 us; speedup vs baseline: 1.0110x; 1.0110x over previous
//
#include <hip/hip_runtime.h>
#include <stdint.h>

typedef __attribute__((ext_vector_type(8))) short short8;
typedef __attribute__((ext_vector_type(4))) float f32x4;

// Problem constants (fixed by the reference): B=2048 traj, T=32, I=H=1024
#define NTRAJ 2048
#define TSTEP 32
#define HDIM  1024
#define KCAT  2048   // I + H
#define NGATE 4096   // 4*H

__device__ __forceinline__ unsigned short f2bf(float f) {
  union { float f; unsigned int u; } v; v.f = f;
  unsigned int u = v.u + 0x7FFFu + ((v.u >> 16) & 1u);   // RNE
  return (unsigned short)(u >> 16);
}
__device__ __forceinline__ float sigmoidf_(float x) {
  return 1.0f / (1.0f + __expf(-x));
}
__device__ __forceinline__ float tanhf_(float x) {
  return 1.0f - 2.0f / (__expf(2.0f * x) + 1.0f);
}

// async global -> LDS, 16B per lane. LDS dest is wave-uniform base + lane*16.
__device__ __forceinline__ void async_lds16(const void* g, void* l) {
  __builtin_amdgcn_global_load_lds(
      (const __attribute__((address_space(1))) unsigned int*)g,
      (__attribute__((address_space(3))) unsigned int*)l, 16, 0, 0);
}

// ---------------- prep kernels ----------------

// fp32 -> bf16 AND transpose to time-major X[t][traj][1024]
__global__ void cvt_bf16_kernel(const float* __restrict__ src,
                                unsigned short* __restrict__ dst, int n4) {
  int i = blockIdx.x * blockDim.x + threadIdx.x;
  if (i >= n4) return;
  float4 v = ((const float4*)src)[i];
  int e = i * 4;
  int row = e >> 10;            // traj*32 + t
  int col = e & 1023;
  int traj = row >> 5, tt = row & 31;
  size_t de = (((size_t)tt * 2048 + traj) << 10) + col;
  ushort4 o;
  o.x = f2bf(v.x); o.y = f2bf(v.y); o.z = f2bf(v.z); o.w = f2bf(v.w);
  *(ushort4*)&dst[de] = o;
}

// Build Wcat[4096][2048] bf16 = [w_ih | w_hh] (both stored row-major [4096][1024])
__global__ void wcat_kernel(const float* __restrict__ wih,
                            const float* __restrict__ whh,
                            unsigned short* __restrict__ wcat) {
  int i = blockIdx.x * blockDim.x + threadIdx.x;   // float4 index, 2,097,152 total
  int e = i * 4;
  int row = e >> 11;           // /2048
  int col = e & 2047;
  const float* src = (col < 1024) ? (wih + (size_t)row * 1024 + col)
                                  : (whh + (size_t)row * 1024 + (col - 1024));
  float4 v = *(const float4*)src;
  ushort4 o;
  o.x = f2bf(v.x); o.y = f2bf(v.y); o.z = f2bf(v.z); o.w = f2bf(v.w);
  ((ushort4*)wcat)[i] = o;
}

// h0 (bf16), c0 (fp32), bias = b_ih + b_hh
__global__ void state_prep(const float* __restrict__ rnn,
                           const float* __restrict__ bih,
                           const float* __restrict__ bhh,
                           unsigned short* __restrict__ h0,
                           float* __restrict__ c0,
                           float* __restrict__ bias) {
  int i = blockIdx.x * blockDim.x + threadIdx.x;   // 0..2097151
  int b = i >> 10, j = i & 1023;
  float hv = rnn[(size_t)b * 2048 + j];
  float cv = rnn[(size_t)b * 2048 + 1024 + j];
  h0[i] = f2bf(hv);
  c0[i] = cv;
  if (i < 4096) bias[i] = bih[i] + bhh[i];
}

// ---------------- fused recurrent step ----------------
// gates = [x_t | h] @ Wcat^T + bias ; LSTM cell update fused, register-local.
// Block: 256 thr (4 waves). Wave w owns 64 batch rows x 16 h-cols x ALL 4 gates.
// XCD-aware mapping: XCD k owns column-groups y in {2k,2k+1} -> 2MB B set in L2.
//
// Pipeline (T4 counted-vmcnt, depth 2, 3 LDS buffers, 60KB):
//   iteration j: issue stage(j+2) -> buf[(j+2)%3]; s_waitcnt vmcnt(10)
//   (counted: waits ONLY for stage(j)'s 5 loads, issued 2 iterations ago --
//   never drains the in-flight prefetches); s_barrier; ds_read+MFMA on
//   buf[j%3]; s_barrier. Loads get ~2 compute phases to land. FIFO vmcnt
//   semantics make the counted wait exact (m135). __syncthreads (vmcnt(0)
//   drain) is never executed in the main loop.
__global__ __launch_bounds__(256, 2)
void lstm_step(const unsigned short* __restrict__ X,     // [32][2048][1024] bf16
               const unsigned short* __restrict__ Wcat,  // [4096][2048] bf16
               const float* __restrict__ bias,           // [4096]
               const float* __restrict__ dones,          // [65536]
               const unsigned short* __restrict__ h_in,  // [2048][1024] bf16
               unsigned short* __restrict__ h_out,       // [2048][1024] bf16
               float* __restrict__ cbuf,                 // [2048][1024] fp32
               float* __restrict__ out,                  // x_out [65536][1024]
               float* __restrict__ rnn_out,              // [2048][2048]
               int t) {
  __shared__ __align__(16) unsigned short Ab[3][64 * 32];       // 3 x 4KB
  __shared__ __align__(16) unsigned short Bb[3][4 * 64 * 32];   // 3 x 16KB

  const int tid  = threadIdx.x;
  const int wave = tid >> 6;
  const int lane = tid & 63;
  const int l16  = lane & 15;
  const int quad = lane >> 4;

  // XCD-aware block decode (bijective over 512 blocks; HW round-robins s&7)
  const int sbid = blockIdx.x;       // 0..511
  const int xcd  = sbid & 7;
  const int ii   = sbid >> 3;        // 0..63
  const int by   = (xcd << 1) | (ii >> 5);   // 0..15  (col group)
  const int bx   = ii & 31;                  // 0..31  (batch group)
  const int bBase = bx * 64;   // batch rows
  const int n0    = by * 64;   // cols within one gate (0..1023)

  // this thread's output column (C layout col = lane&15)
  const int col = n0 + wave * 16 + l16;

  // swizzled read slot: logical slot `quad` of row l16 lives at sq
  const int sq = quad ^ ((l16 >> 1) & 3);

  // accumulators init with bias
  f32x4 acc[4][4];
#pragma unroll
  for (int g = 0; g < 4; ++g) {
    float bv = bias[g * 1024 + col];
    f32x4 b4 = {bv, bv, bv, bv};
#pragma unroll
    for (int mt = 0; mt < 4; ++mt) acc[mt][g] = b4;
  }

  // staging: 1KB chunk = 16 rows x 32 bf16. Linear LDS dest (lane*16B) means
  // LDS slot (lr, lane&3) receives the global slot we point at -> pre-swizzle
  // the per-lane global source slot so LDS holds the swizzled layout.
  const int lr = lane >> 2;
  const int lc = ((lane & 3) ^ ((lr >> 1) & 3)) * 8;   // pre-swizzled source col
  const unsigned short* aX =
      X + (((size_t)t * 2048) + bBase + wave * 16 + lr) * 1024 + lc;
  const unsigned short* aH =
      h_in + (size_t)(bBase + wave * 16 + lr) * 1024 + lc;

  const unsigned short* bS[4];
#pragma unroll
  for (int q = 0; q < 4; ++q) {
    int cb = wave + 4 * q;                       // B chunk id (g = q, rowblk = wave)
    int g  = cb >> 2;
    int row = g * 1024 + n0 + (cb & 3) * 16 + lr;
    bS[q] = Wcat + (size_t)row * 2048 + lc;
  }

  // stage K-step j into buffer b (5 global_load_lds per wave)
  auto stage = [&](int j, int b) {
    const unsigned short* as =
        (j < 32) ? (aX + (size_t)j * 32) : (aH + (size_t)(j - 32) * 32);
    async_lds16(as, &Ab[b][wave * 512]);
#pragma unroll
    for (int q = 0; q < 4; ++q)
      async_lds16(bS[q] + (size_t)j * 32, &Bb[b][(wave + 4 * q) * 512]);
  };

  // compute K-step from buffer b
  auto compute = [&](int b) {
    short8 fa[4], fb[4];
#pragma unroll
    for (int mt = 0; mt < 4; ++mt)
      fa[mt] = *(const short8*)&Ab[b][mt * 512 + l16 * 32 + sq * 8];
#pragma unroll
    for (int g = 0; g < 4; ++g)
      fb[g] = *(const short8*)&Bb[b][(g * 4 + wave) * 512 + l16 * 32 + sq * 8];
#pragma unroll
    for (int mt = 0; mt < 4; ++mt)
#pragma unroll
      for (int g = 0; g < 4; ++g)
        acc[mt][g] = __builtin_amdgcn_mfma_f32_16x16x32_bf16(fa[mt], fb[g],
                                                             acc[mt][g], 0, 0, 0);
  };

  // prologue: 2 stages in flight before first compute
  stage(0, 0);
  stage(1, 1);

  for (int j = 0; j < 64; ++j) {
    const int cur = j % 3;
    if (j < 62) {
      stage(j + 2, (j + 2) % 3);
      // outstanding <= {j, j+1, j+2} = 15 loads; leave 10 newest in flight
      // -> stage(j)'s loads (oldest) have landed.
      asm volatile("s_waitcnt vmcnt(10)" ::: "memory");
    } else if (j == 62) {
      // outstanding <= {62, 63} = 10; leave 5 -> stage(62) landed
      asm volatile("s_waitcnt vmcnt(5)" ::: "memory");
    } else {
      asm volatile("s_waitcnt vmcnt(0)" ::: "memory");
    }
    __builtin_amdgcn_s_barrier();   // buf[cur] ready for every wave
    compute(cur);
    __builtin_amdgcn_s_barrier();   // all reads of buf[cur] done; next
                                    // iteration may overwrite buf[(j+3)%3]==cur
  }

  // epilogue: fully register-local. lane holds rows mt*16+quad*4+v, col `col`.
#pragma unroll
  for (int mt = 0; mt < 4; ++mt) {
#pragma unroll
    for (int v = 0; v < 4; ++v) {
      int b = bBase + mt * 16 + quad * 4 + v;
      float gi = sigmoidf_(acc[mt][0][v]);
      float gf = sigmoidf_(acc[mt][1][v]);
      float gg = tanhf_  (acc[mt][2][v]);
      float go = sigmoidf_(acc[mt][3][v]);
      float cold = cbuf[(size_t)b * 1024 + col];
      float cn = gf * cold + gi * gg;
      float hn = go * tanhf_(cn);
      out[((size_t)b * 32 + t) * 1024 + col] = hn;       // x_out (pre-reset h)
      // fold NEXT step's reset into the carries; step t+1 reset = dones[b*32+t]
      float keep = (t < 31) ? (1.0f - dones[b * 32 + t]) : 1.0f;
      cbuf[(size_t)b * 1024 + col] = cn * keep;
      h_out[(size_t)b * 1024 + col] = f2bf(hn * keep);
      if (t == 31) {                                      // final states, un-reset
        rnn_out[(size_t)b * 2048 + col] = hn;
        rnn_out[(size_t)b * 2048 + 1024 + col] = cn;
      }
    }
  }
}

// ---------------- launcher ----------------
extern "C" void kernel_launch(void* const* d_in, const int* in_sizes, int n_in,
                              void* d_out, int out_size, void* d_ws, size_t ws_size,
                              hipStream_t stream) {
  (void)in_sizes; (void)n_in; (void)out_size; (void)ws_size;
  const float* head  = (const float*)d_in[0];  // [65536][1024]
  const float* rnn   = (const float*)d_in[1];  // [2048][2048]
  const float* dones = (const float*)d_in[2];  // [65536]
  const float* wih   = (const float*)d_in[3];  // [4096][1024]
  const float* whh   = (const float*)d_in[4];  // [4096][1024]
  const float* bih   = (const float*)d_in[5];  // [4096]
  const float* bhh   = (const float*)d_in[6];  // [4096]
  float* out = (float*)d_out;
  float* rnn_out = out + (size_t)65536 * 1024;

  char* ws = (char*)d_ws;
  unsigned short* X    = (unsigned short*)(ws);                 // 128 MB (time-major)
  unsigned short* Wcat = (unsigned short*)(ws + 134217728);     // 16 MB
  float*          bias = (float*)(ws + 150994944);              // 16 KB
  unsigned short* h0   = (unsigned short*)(ws + 151011328);     // 4 MB
  unsigned short* h1   = (unsigned short*)(ws + 155205632);     // 4 MB
  float*          cbuf = (float*)(ws + 159399936);              // 8 MB
  // total ws use: ~160 MB

  cvt_bf16_kernel<<<65536, 256, 0, stream>>>(head, X, 16777216);
  wcat_kernel<<<8192, 256, 0, stream>>>(wih, whh, Wcat);
  state_prep<<<8192, 256, 0, stream>>>(rnn, bih, bhh, h0, cbuf, bias);

  unsigned short* hb[2] = {h0, h1};
  for (int t = 0; t < TSTEP; ++t) {
    lstm_step<<<512, 256, 0, stream>>>(
        X, Wcat, bias, dones, hb[t & 1], hb[(t + 1) & 1], cbuf, out, rnn_out, t);
  }
}

// Round 7
// 2396.840 us; speedup vs baseline: 1.1187x; 1.1065x over previous
//
#include <hip/hip_runtime.h>
#include <stdint.h>

typedef __attribute__((ext_vector_type(8))) short short8;
typedef __attribute__((ext_vector_type(4))) float f32x4;

// Problem constants (fixed by the reference): B=2048 traj, T=32, I=H=1024
#define NTRAJ 2048
#define TSTEP 32
#define HDIM  1024
#define KCAT  2048   // I + H
#define NGATE 4096   // 4*H

__device__ __forceinline__ unsigned short f2bf(float f) {
  union { float f; unsigned int u; } v; v.f = f;
  unsigned int u = v.u + 0x7FFFu + ((v.u >> 16) & 1u);   // RNE
  return (unsigned short)(u >> 16);
}
__device__ __forceinline__ float sigmoidf_(float x) {
  return 1.0f / (1.0f + __expf(-x));
}
__device__ __forceinline__ float tanhf_(float x) {
  return 1.0f - 2.0f / (__expf(2.0f * x) + 1.0f);
}

// async global -> LDS, 16B per lane. LDS dest is wave-uniform base + lane*16.
__device__ __forceinline__ void async_lds16(const void* g, void* l) {
  __builtin_amdgcn_global_load_lds(
      (const __attribute__((address_space(1))) unsigned int*)g,
      (__attribute__((address_space(3))) unsigned int*)l, 16, 0, 0);
}

// ---------------- prep kernels ----------------

// fp32 -> bf16 AND transpose to time-major X[t][traj][1024]
__global__ void cvt_bf16_kernel(const float* __restrict__ src,
                                unsigned short* __restrict__ dst, int n4) {
  int i = blockIdx.x * blockDim.x + threadIdx.x;
  if (i >= n4) return;
  float4 v = ((const float4*)src)[i];
  int e = i * 4;
  int row = e >> 10;            // traj*32 + t
  int col = e & 1023;
  int traj = row >> 5, tt = row & 31;
  size_t de = (((size_t)tt * 2048 + traj) << 10) + col;
  ushort4 o;
  o.x = f2bf(v.x); o.y = f2bf(v.y); o.z = f2bf(v.z); o.w = f2bf(v.w);
  *(ushort4*)&dst[de] = o;
}

// Build Wcat[4096][2048] bf16 = [w_ih | w_hh] (both stored row-major [4096][1024])
__global__ void wcat_kernel(const float* __restrict__ wih,
                            const float* __restrict__ whh,
                            unsigned short* __restrict__ wcat) {
  int i = blockIdx.x * blockDim.x + threadIdx.x;   // float4 index, 2,097,152 total
  int e = i * 4;
  int row = e >> 11;           // /2048
  int col = e & 2047;
  const float* src = (col < 1024) ? (wih + (size_t)row * 1024 + col)
                                  : (whh + (size_t)row * 1024 + (col - 1024));
  float4 v = *(const float4*)src;
  ushort4 o;
  o.x = f2bf(v.x); o.y = f2bf(v.y); o.z = f2bf(v.z); o.w = f2bf(v.w);
  ((ushort4*)wcat)[i] = o;
}

// h0 (bf16), c0 (fp32), bias = b_ih + b_hh
__global__ void state_prep(const float* __restrict__ rnn,
                           const float* __restrict__ bih,
                           const float* __restrict__ bhh,
                           unsigned short* __restrict__ h0,
                           float* __restrict__ c0,
                           float* __restrict__ bias) {
  int i = blockIdx.x * blockDim.x + threadIdx.x;   // 0..2097151
  int b = i >> 10, j = i & 1023;
  float hv = rnn[(size_t)b * 2048 + j];
  float cv = rnn[(size_t)b * 2048 + 1024 + j];
  h0[i] = f2bf(hv);
  c0[i] = cv;
  if (i < 4096) bias[i] = bih[i] + bhh[i];
}

// ---------------- fused recurrent step ----------------
// gates = [x_t | h] @ Wcat^T + bias ; LSTM cell update fused, register-local.
//
// OCCUPANCY round: 512 thr (8 waves), same M=64 x N=256(4 gates) tile, same
// grid 512, same traffic. Wave (wr,wc): wr=wave>>2 owns m-half (32 rows),
// wc=wave&3 owns 16-col slice of each gate; acc[2][4] (32 VGPR). LDS 40KB
// (2-buffer) -> 2 blocks/CU -> 16 waves/CU = 4/SIMD (was 8/CU = 2/SIMD).
// Rounds 3/5 proved explicit pipelining null at 2 waves/SIMD: post-barrier
// latency is hidden only by OTHER waves (m114/m131). This doubles them.
// XCD-aware mapping: XCD k owns column-groups y in {2k,2k+1} -> 2MB B in L2.
__global__ __launch_bounds__(512, 4)
void lstm_step(const unsigned short* __restrict__ X,     // [32][2048][1024] bf16
               const unsigned short* __restrict__ Wcat,  // [4096][2048] bf16
               const float* __restrict__ bias,           // [4096]
               const float* __restrict__ dones,          // [65536]
               const unsigned short* __restrict__ h_in,  // [2048][1024] bf16
               unsigned short* __restrict__ h_out,       // [2048][1024] bf16
               float* __restrict__ cbuf,                 // [2048][1024] fp32
               float* __restrict__ out,                  // x_out [65536][1024]
               float* __restrict__ rnn_out,              // [2048][2048]
               int t) {
  __shared__ __align__(16) unsigned short Ab[2][64 * 32];       // 2 x 4KB
  __shared__ __align__(16) unsigned short Bb[2][16 * 512];      // 2 x 16KB

  const int tid  = threadIdx.x;
  const int wave = tid >> 6;        // 0..7
  const int lane = tid & 63;
  const int l16  = lane & 15;
  const int quad = lane >> 4;
  const int wr   = wave >> 2;       // m-half (0..1)
  const int wc   = wave & 3;        // col-slice (0..3)

  // XCD-aware block decode (bijective over 512 blocks; HW round-robins s&7)
  const int sbid = blockIdx.x;       // 0..511
  const int xcd  = sbid & 7;
  const int ii   = sbid >> 3;        // 0..63
  const int by   = (xcd << 1) | (ii >> 5);   // 0..15  (col group)
  const int bx   = ii & 31;                  // 0..31  (batch group)
  const int bBase = bx * 64;   // batch rows
  const int n0    = by * 64;   // cols within one gate (0..1023)

  // this thread's output column (C layout col = lane&15)
  const int col = n0 + wc * 16 + l16;

  // swizzled read slot: logical slot `quad` of row l16 lives at sq
  const int sq = quad ^ ((l16 >> 1) & 3);

  // accumulators init with bias
  f32x4 acc[2][4];
#pragma unroll
  for (int g = 0; g < 4; ++g) {
    float bv = bias[g * 1024 + col];
    f32x4 b4 = {bv, bv, bv, bv};
#pragma unroll
    for (int mt = 0; mt < 2; ++mt) acc[mt][g] = b4;
  }

  // staging: 1KB chunk = 16 rows x 32 bf16. Linear LDS dest (lane*16B) means
  // LDS slot (lr, lane&3) receives the global slot we point at -> pre-swizzle
  // the per-lane global source slot so LDS holds the swizzled layout.
  const int lr = lane >> 2;
  const int lc = ((lane & 3) ^ ((lr >> 1) & 3)) * 8;   // pre-swizzled source col
  // A: waves 0..3 stage chunk `wave` (rows wave*16+lr)
  const unsigned short* aX =
      X + (((size_t)t * 2048) + bBase + wave * 16 + lr) * 1024 + lc;
  const unsigned short* aH =
      h_in + (size_t)(bBase + wave * 16 + lr) * 1024 + lc;
  // B: each wave stages 2 chunks: cb = wave*2+q; chunk cb = gate cb>>2,
  // col-block cb&3 (16 output-cols), rows lr.
  const unsigned short* bS[2];
#pragma unroll
  for (int q = 0; q < 2; ++q) {
    int cb = wave * 2 + q;
    int g  = cb >> 2;
    int row = g * 1024 + n0 + (cb & 3) * 16 + lr;
    bS[q] = Wcat + (size_t)row * 2048 + lc;
  }

  // stage K-step j into buffer b (2-3 global_load_lds per wave)
  auto stage = [&](int j, int b) {
    if (wave < 4) {
      const unsigned short* as =
          (j < 32) ? (aX + (size_t)j * 32) : (aH + (size_t)(j - 32) * 32);
      async_lds16(as, &Ab[b][wave * 512]);
    }
#pragma unroll
    for (int q = 0; q < 2; ++q)
      async_lds16(bS[q] + (size_t)j * 32, &Bb[b][(wave * 2 + q) * 512]);
  };

  // compute K-step from buffer b
  auto compute = [&](int b) {
    short8 fa[2], fb[4];
#pragma unroll
    for (int mt = 0; mt < 2; ++mt)
      fa[mt] = *(const short8*)&Ab[b][(wr * 32 + mt * 16 + l16) * 32 + sq * 8];
#pragma unroll
    for (int g = 0; g < 4; ++g)
      fb[g] = *(const short8*)&Bb[b][(g * 4 + wc) * 512 + l16 * 32 + sq * 8];
#pragma unroll
    for (int mt = 0; mt < 2; ++mt)
#pragma unroll
      for (int g = 0; g < 4; ++g)
        acc[mt][g] = __builtin_amdgcn_mfma_f32_16x16x32_bf16(fa[mt], fb[g],
                                                             acc[mt][g], 0, 0, 0);
  };

  // 2-buffer pipeline, one __syncthreads per K-step; TLP (16 waves/CU)
  // provides the latency hiding (m114).
  stage(0, 0);
  __syncthreads();
  for (int j = 0; j < 64; ++j) {
    const int cur = j & 1;
    if (j < 63) stage(j + 1, cur ^ 1);   // prefetch next K-step
    compute(cur);
    __syncthreads();                      // prefetch landed; reads of cur done
  }

  // epilogue: fully register-local. lane holds rows wr*32+mt*16+quad*4+v,
  // col `col`, for all 4 gates.
#pragma unroll
  for (int mt = 0; mt < 2; ++mt) {
#pragma unroll
    for (int v = 0; v < 4; ++v) {
      int b = bBase + wr * 32 + mt * 16 + quad * 4 + v;
      float gi = sigmoidf_(acc[mt][0][v]);
      float gf = sigmoidf_(acc[mt][1][v]);
      float gg = tanhf_  (acc[mt][2][v]);
      float go = sigmoidf_(acc[mt][3][v]);
      float cold = cbuf[(size_t)b * 1024 + col];
      float cn = gf * cold + gi * gg;
      float hn = go * tanhf_(cn);
      out[((size_t)b * 32 + t) * 1024 + col] = hn;       // x_out (pre-reset h)
      // fold NEXT step's reset into the carries; step t+1 reset = dones[b*32+t]
      float keep = (t < 31) ? (1.0f - dones[b * 32 + t]) : 1.0f;
      cbuf[(size_t)b * 1024 + col] = cn * keep;
      h_out[(size_t)b * 1024 + col] = f2bf(hn * keep);
      if (t == 31) {                                      // final states, un-reset
        rnn_out[(size_t)b * 2048 + col] = hn;
        rnn_out[(size_t)b * 2048 + 1024 + col] = cn;
      }
    }
  }
}

// ---------------- launcher ----------------
extern "C" void kernel_launch(void* const* d_in, const int* in_sizes, int n_in,
                              void* d_out, int out_size, void* d_ws, size_t ws_size,
                              hipStream_t stream) {
  (void)in_sizes; (void)n_in; (void)out_size; (void)ws_size;
  const float* head  = (const float*)d_in[0];  // [65536][1024]
  const float* rnn   = (const float*)d_in[1];  // [2048][2048]
  const float* dones = (const float*)d_in[2];  // [65536]
  const float* wih   = (const float*)d_in[3];  // [4096][1024]
  const float* whh   = (const float*)d_in[4];  // [4096][1024]
  const float* bih   = (const float*)d_in[5];  // [4096]
  const float* bhh   = (const float*)d_in[6];  // [4096]
  float* out = (float*)d_out;
  float* rnn_out = out + (size_t)65536 * 1024;

  char* ws = (char*)d_ws;
  unsigned short* X    = (unsigned short*)(ws);                 // 128 MB (time-major)
  unsigned short* Wcat = (unsigned short*)(ws + 134217728);     // 16 MB
  float*          bias = (float*)(ws + 150994944);              // 16 KB
  unsigned short* h0   = (unsigned short*)(ws + 151011328);     // 4 MB
  unsigned short* h1   = (unsigned short*)(ws + 155205632);     // 4 MB
  float*          cbuf = (float*)(ws + 159399936);              // 8 MB
  // total ws use: ~160 MB

  cvt_bf16_kernel<<<65536, 256, 0, stream>>>(head, X, 16777216);
  wcat_kernel<<<8192, 256, 0, stream>>>(wih, whh, Wcat);
  state_prep<<<8192, 256, 0, stream>>>(rnn, bih, bhh, h0, cbuf, bias);

  unsigned short* hb[2] = {h0, h1};
  for (int t = 0; t < TSTEP; ++t) {
    lstm_step<<<512, 512, 0, stream>>>(
        X, Wcat, bias, dones, hb[t & 1], hb[(t + 1) & 1], cbuf, out, rnn_out, t);
  }
}